// Round 8
// baseline (150.301 us; speedup 1.0000x reference)
//
#include <hip/hip_runtime.h>
#include <math.h>
#include <stdint.h>

#define B 8
#define C 64
#define H 256
#define W 256
#define NPLANE 16            // 2 inputs x 8 batches
#define PSZ (H * W)          // 65536

// workspace layout
#define OFF_WC    256                        // 2*64*9 f64 = 9216 B
#define OFF_BIAS  9728                       // 2 f64
#define OFF_F     16384                      // 16*PSZ f64 = 8388608 B

// ---------------------------------------------------------------------------
// async global->LDS, 16B per lane. Cast generic pointers to AS-qualified
// pointers via uintptr_t (integer->AS-pointer casts are allowed; direct
// pointer reinterpret_cast is not).
// LDS dest is wave-uniform base + lane*16; global src is per-lane.
// ---------------------------------------------------------------------------
typedef const __attribute__((address_space(1))) char* as1_cptr;
typedef __attribute__((address_space(3))) char* as3_ptr;

__device__ __forceinline__ void gload_lds16(const float* g, float* l) {
    __builtin_amdgcn_global_load_lds((as1_cptr)(uintptr_t)g,
                                     (as3_ptr)(uintptr_t)l, 16, 0, 0);
}

// ---------------------------------------------------------------------------
// prep: fold pointwise weight into depthwise taps (f64), fold biases.
// ---------------------------------------------------------------------------
__global__ void prep_kernel(const float* __restrict__ dw_w0, const float* __restrict__ dw_b0,
                            const float* __restrict__ pw_w0, const float* __restrict__ pw_b0,
                            const float* __restrict__ dw_w1, const float* __restrict__ dw_b1,
                            const float* __restrict__ pw_w1, const float* __restrict__ pw_b1,
                            double* __restrict__ wc, double* __restrict__ bias)
{
    int t = threadIdx.x;            // 0..127
    int which = t >> 6, c = t & 63;
    const float* dw = which ? dw_w1 : dw_w0;
    const float* pw = which ? pw_w1 : pw_w0;
    double p = (double)pw[c];
    #pragma unroll
    for (int k = 0; k < 9; ++k)
        wc[(which * 64 + c) * 9 + k] = p * (double)dw[c * 9 + k];
    if (c == 0) {
        const float* dwb = which ? dw_b1 : dw_b0;
        const float* pwb = which ? pw_b1 : pw_b0;
        double acc = (double)pwb[0];
        for (int cc = 0; cc < 64; ++cc) acc += (double)pw[cc] * (double)dwb[cc];
        bias[which] = acc;
    }
}

// ---------------------------------------------------------------------------
// per-channel compute from a staged 6-row LDS buffer.
// JLO/JHI restrict valid input rows at image top/bottom (zero padding).
// ---------------------------------------------------------------------------
template<int JLO, int JHI>
__device__ __forceinline__ void compute_channel(
    const float* buf,               // 6 rows x 256 floats (LDS)
    const double* __restrict__ w9g, // 9 folded weights (global, wave-uniform)
    int lane, double acc[4][4])
{
    double wl[9];
    #pragma unroll
    for (int t = 0; t < 9; ++t) wl[t] = w9g[t];

    #pragma unroll
    for (int j = 0; j < 6; ++j) {
        if (j < JLO || j > JHI) continue;
        float4 v = *(const float4*)(buf + j * 256 + lane * 4);
        float lf = __shfl_up(v.w, 1);
        float rf = __shfl_down(v.x, 1);
        if (lane == 0)  lf = 0.0f;
        if (lane == 63) rf = 0.0f;
        double dd[6] = {(double)lf, (double)v.x, (double)v.y,
                        (double)v.z, (double)v.w, (double)rf};
        #pragma unroll
        for (int i = 0; i < 3; ++i) {
            const int o = j - i;                 // output row
            if (o >= 0 && o < 4) {
                double wa = wl[3 * i], wb = wl[3 * i + 1], wcv = wl[3 * i + 2];
                #pragma unroll
                for (int k = 0; k < 4; ++k)
                    acc[o][k] += wa * dd[k] + wb * dd[k + 1] + wcv * dd[k + 2];
            }
        }
    }
}

// 16-channel loop with 2-deep LDS double buffer and counted vmcnt.
template<int JLO, int JHI>
__device__ __forceinline__ void channel_loop(
    const float* gl,                // x plane base + lane*4
    float* stage,                   // this wave's 2x1536-float staging area
    const double* __restrict__ wp,  // folded weights for this input
    int cbase, const int gy[6], int lane, double acc[4][4])
{
    // prologue: stage first channel into buf 0
    #pragma unroll
    for (int j = 0; j < 6; ++j)
        gload_lds16(gl + (size_t)cbase * PSZ + gy[j] * W, stage + j * 256);

    #pragma unroll 1
    for (int cc = 0; cc < 16; ++cc) {
        if (cc + 1 < 16) {
            const float* gsrc = gl + (size_t)(cbase + cc + 1) * PSZ;
            float* dbuf = stage + ((cc + 1) & 1) * 1536;
            #pragma unroll
            for (int j = 0; j < 6; ++j)
                gload_lds16(gsrc + gy[j] * W, dbuf + j * 256);
            // 12 outstanding; wait until <=6 so the previous channel is ready,
            // next channel's 6 stay in flight under the compute.
            asm volatile("s_waitcnt vmcnt(6)" ::: "memory");
        } else {
            asm volatile("s_waitcnt vmcnt(0)" ::: "memory");
        }
        __builtin_amdgcn_sched_barrier(0);
        compute_channel<JLO, JHI>(stage + (cc & 1) * 1536,
                                  wp + (size_t)(cbase + cc) * 9, lane, acc);
    }
}

// ---------------------------------------------------------------------------
// score: block = (plane, 4-row band). 4 waves x 16 channels each, no barriers
// in the hot loop (waves fully independent; LDS staging is per-wave private).
// f64 end-to-end so the argmax selection matches the f64 numpy reference.
// ---------------------------------------------------------------------------
__global__ __launch_bounds__(256) void score_band_kernel(
    const float* __restrict__ x0, const float* __restrict__ x1,
    const double* __restrict__ wc, const double* __restrict__ bias,
    double* __restrict__ f)
{
    __shared__ double smem[6144];   // 48 KiB: 4 waves x 2 bufs x 6 KiB; reused for reduction

    // XCD-bijective swizzle: adjacent bands land on the same XCD (L2 halo reuse).
    const int n     = blockIdx.x;
    const int task  = (n & 7) * 128 + (n >> 3);
    const int plane = task >> 6;         // 0..15
    const int band  = task & 63;         // 0..63
    const int which = plane >> 3;
    const int b     = plane & 7;
    const int y0    = band * 4;

    const int w    = threadIdx.x >> 6;   // wave 0..3
    const int lane = threadIdx.x & 63;

    float* stage = (float*)smem + w * 3072;        // private 12 KiB / wave

    const float*  xp = (which ? x1 : x0) + (size_t)b * C * PSZ;
    const double* wp = wc + which * (C * 9);
    const int cbase  = w * 16;
    const float* gl  = xp + lane * 4;

    int gy[6];
    #pragma unroll
    for (int j = 0; j < 6; ++j) {
        int r = y0 - 1 + j;
        gy[j] = r < 0 ? 0 : (r > H - 1 ? H - 1 : r);   // clamped (edge rows skipped in compute)
    }

    double acc[4][4] = {};   // [out-row][px]

    if (band == 0)            channel_loop<1, 5>(gl, stage, wp, cbase, gy, lane, acc);
    else if (band == 63)      channel_loop<0, 4>(gl, stage, wp, cbase, gy, lane, acc);
    else                      channel_loop<0, 5>(gl, stage, wp, cbase, gy, lane, acc);

    // deterministic cross-wave reduction, reusing the staging LDS.
    __syncthreads();
    double* sred = smem;   // [wave][o][k][lane]
    #pragma unroll
    for (int o = 0; o < 4; ++o)
        #pragma unroll
        for (int k = 0; k < 4; ++k)
            sred[((w * 4 + o) * 4 + k) * 64 + lane] = acc[o][k];
    __syncthreads();

    const double bv = bias[which];
    double* fp = f + (size_t)plane * PSZ + (size_t)(y0 + w) * W + lane * 4;
    #pragma unroll
    for (int k = 0; k < 4; ++k) {
        double s = sred[((0 * 4 + w) * 4 + k) * 64 + lane]
                 + sred[((1 * 4 + w) * 4 + k) * 64 + lane]
                 + sred[((2 * 4 + w) * 4 + k) * 64 + lane]
                 + sred[((3 * 4 + w) * 4 + k) * 64 + lane] + bv;
        fp[k] = 1.0 + 1.0 / (1.0 + exp(-s));
    }
}

// ---------------------------------------------------------------------------
// Selection. block = one (b,y) row; 256 threads = 64 float4-cols x 4 channel
// groups. f-row values live in registers, reused over 16 channels.
// ---------------------------------------------------------------------------
__global__ __launch_bounds__(256) void select_kernel(
    const float*  __restrict__ x0,
    const float*  __restrict__ x1,
    const double* __restrict__ f0,
    const double* __restrict__ f1,
    float* __restrict__ out,
    unsigned int* __restrict__ count1)
{
    const int by = blockIdx.x;        // 0 .. B*H-1
    const int b  = by >> 8;
    const int y  = by & (H - 1);
    const int tx = threadIdx.x & 63;
    const int tc = threadIdx.x >> 6;

    const size_t plane = (size_t)b * H * W + (size_t)y * W + (size_t)tx * 4;
    double g0[4], g1[4];
    #pragma unroll
    for (int j = 0; j < 4; ++j) { g0[j] = f0[plane + j]; g1[j] = f1[plane + j]; }

    const size_t rowbase = (size_t)b * C * H * W + (size_t)y * W + (size_t)tx * 4;

    unsigned int cnt = 0;
    for (int ci = tc; ci < C; ci += 4) {
        size_t off = rowbase + (size_t)ci * H * W;
        float4 a  = *(const float4*)(x0 + off);
        float4 bb = *(const float4*)(x1 + off);
        float4 r;
        { double w0=(double)a.x*g0[0], w1=(double)bb.x*g1[0]; bool s1=(w1>w0); cnt+=s1; r.x=s1?bb.x:a.x; }
        { double w0=(double)a.y*g0[1], w1=(double)bb.y*g1[1]; bool s1=(w1>w0); cnt+=s1; r.y=s1?bb.y:a.y; }
        { double w0=(double)a.z*g0[2], w1=(double)bb.z*g1[2]; bool s1=(w1>w0); cnt+=s1; r.z=s1?bb.z:a.z; }
        { double w0=(double)a.w*g0[3], w1=(double)bb.w*g1[3]; bool s1=(w1>w0); cnt+=s1; r.w=s1?bb.w:a.w; }
        *(float4*)(out + off) = r;
    }

    __shared__ unsigned int blk;
    if (threadIdx.x == 0) blk = 0;
    __syncthreads();
    atomicAdd(&blk, cnt);
    __syncthreads();
    if (threadIdx.x == 0) atomicAdd(count1, blk);
}

__global__ void finalize_kernel(const unsigned int* __restrict__ count1,
                                float* __restrict__ out_p)
{
    const double N = (double)B * C * H * W;
    double c1 = (double)(*count1);
    out_p[0] = (float)((N - c1) / N);
    out_p[1] = (float)(c1 / N);
}

extern "C" void kernel_launch(void* const* d_in, const int* in_sizes, int n_in,
                              void* d_out, int out_size, void* d_ws, size_t ws_size,
                              hipStream_t stream) {
    const float* x0    = (const float*)d_in[0];
    const float* x1    = (const float*)d_in[1];
    const float* dw_w0 = (const float*)d_in[2];
    const float* dw_b0 = (const float*)d_in[3];
    const float* pw_w0 = (const float*)d_in[4];
    const float* pw_b0 = (const float*)d_in[5];
    const float* dw_w1 = (const float*)d_in[6];
    const float* dw_b1 = (const float*)d_in[7];
    const float* pw_w1 = (const float*)d_in[8];
    const float* pw_b1 = (const float*)d_in[9];
    float* out = (float*)d_out;

    unsigned int* cnt  = (unsigned int*)d_ws;
    double*       wc   = (double*)((char*)d_ws + OFF_WC);
    double*       bias = (double*)((char*)d_ws + OFF_BIAS);
    double*       f    = (double*)((char*)d_ws + OFF_F);
    double*       f0   = f;                       // planes 0..7  (input 0)
    double*       f1   = f + (size_t)8 * PSZ;     // planes 8..15 (input 1)

    (void)hipMemsetAsync(d_ws, 0, 256, stream);

    prep_kernel<<<1, 128, 0, stream>>>(dw_w0, dw_b0, pw_w0, pw_b0,
                                       dw_w1, dw_b1, pw_w1, pw_b1, wc, bias);

    score_band_kernel<<<NPLANE * (H / 4), 256, 0, stream>>>(x0, x1, wc, bias, f);

    select_kernel<<<B * H, 256, 0, stream>>>(x0, x1, f0, f1, out, cnt);

    finalize_kernel<<<1, 1, 0, stream>>>(cnt, out + (size_t)B * C * H * W);
}